// Round 7
// baseline (131.811 us; speedup 1.0000x reference)
//
#include <hip/hip_runtime.h>
#include <cstddef>
#include <cstdint>

#define B_SZ    32768
#define NTAB    26
#define NROWS   200000

typedef __attribute__((ext_vector_type(8))) short short8v;
typedef __attribute__((ext_vector_type(4))) float f32x4;
typedef __attribute__((ext_vector_type(16))) float f32x16;

__device__ __forceinline__ ushort f2bf(float f) {
    uint32_t u = __builtin_bit_cast(uint32_t, f);
    u += 0x7FFFu + ((u >> 16) & 1u);
    return (ushort)(u >> 16);
}
__device__ __forceinline__ float bf2f(ushort h) {
    uint32_t u = ((uint32_t)h) << 16;
    return __builtin_bit_cast(float, u);
}
__device__ __forceinline__ void stage16(const ushort* g, ushort* l) {
    __builtin_amdgcn_global_load_lds(
        (const __attribute__((address_space(1))) unsigned int*)g,
        (__attribute__((address_space(3))) unsigned int*)l, 16, 0, 0);
}

// All fp32->bf16 conversions (with K->Kp zero pad) in ONE kernel.
__global__ __launch_bounds__(256) void conv_all_k(
    const float* __restrict__ dense_x, const float* __restrict__ bw0,
    const float* __restrict__ tw0, const float* __restrict__ bw1,
    const float* __restrict__ bw2, const float* __restrict__ tw1,
    ushort* __restrict__ dense_pad, ushort* __restrict__ bw0p,
    ushort* __restrict__ tw0p, ushort* __restrict__ bw1c,
    ushort* __restrict__ bw2c, ushort* __restrict__ tw1c)
{
    const int gid = blockIdx.x * 256 + threadIdx.x;
    if (gid < 1048576) {
        int r = gid >> 5, k = gid & 31;
        dense_pad[gid] = (k < 13) ? f2bf(dense_x[r * 13 + k]) : (ushort)0;
    } else if (gid < 1064960) {
        int i = gid - 1048576; int r = i >> 5, k = i & 31;
        bw0p[i] = (k < 13) ? f2bf(bw0[r * 13 + k]) : (ushort)0;
    } else if (gid < 1277952) {
        int i = gid - 1064960; int r = i / 416, k = i - r * 416;
        tw0p[i] = (k < 415) ? f2bf(tw0[r * 415 + k]) : (ushort)0;
    } else if (gid < 1409024) {
        int i = gid - 1277952; bw1c[i] = f2bf(bw1[i]);
    } else if (gid < 1425408) {
        int i = gid - 1409024; bw2c[i] = f2bf(bw2[i]);
    } else if (gid < 1556480) {
        int i = gid - 1425408; tw1c[i] = f2bf(tw1[i]);
    }
}

// ---------------------------------------------------------------------------
// Fused bottom MLP: 13(->32) -> 512 -> 256 -> 64. h0/h1 live only in LDS.
// 32 samples/block, 4 waves, LDS 64 KB -> 2 blocks/CU.
// ---------------------------------------------------------------------------
__global__ __launch_bounds__(256, 2) void bot012_k(
    const ushort* __restrict__ dense_pad, const ushort* __restrict__ bw0p,
    const float* __restrict__ bb0, const ushort* __restrict__ bw1c,
    const float* __restrict__ bb1, const ushort* __restrict__ bw2c,
    const float* __restrict__ bb2, ushort* __restrict__ Rb)
{
    __shared__ __align__(16) ushort h0s[32 * 512];   // 32 KB
    __shared__ __align__(16) ushort Wst[256 * 32];   // 16 KB staging
    __shared__ __align__(16) ushort h1s[32 * 256];   // 16 KB (dense tile overlays at P0)
    const int t = threadIdx.x;
    const int lane = t & 63, w = t >> 6;
    const int fr = lane & 15, j16 = lane >> 4;
    const int bBase = blockIdx.x * 32;

    // stage dense tile (32x32) into h1s region
    if (t < 128) {
        const int r = t >> 2, u = t & 3, us = u ^ ((r >> 1) & 3);
        stage16(dense_pad + (size_t)(bBase + r) * 32 + us * 8, &h1s[t * 8]);
    }

    // P0: h0 = relu(dense @ bw0^T + bb0), K=32, 2 channel halves of 256
    f32x4 acc0[2][2][4] = {};
#pragma unroll
    for (int hh = 0; hh < 2; ++hh) {
#pragma unroll
        for (int i = 0; i < 4; ++i) {
            const int idx = i * 256 + t;
            const int r = idx >> 2, u = idx & 3, us = u ^ ((r >> 1) & 3);
            stage16(bw0p + (size_t)(hh * 256 + r) * 32 + us * 8, &Wst[idx * 8]);
        }
        __syncthreads();
        short8v a[2], b[4];
#pragma unroll
        for (int m = 0; m < 2; ++m) {
            const int r = m * 16 + fr;
            a[m] = *(const short8v*)&h1s[r * 32 + (j16 ^ ((r >> 1) & 3)) * 8];
        }
#pragma unroll
        for (int n = 0; n < 4; ++n) {
            const int lr = w * 64 + n * 16 + fr;
            b[n] = *(const short8v*)&Wst[lr * 32 + (j16 ^ ((lr >> 1) & 3)) * 8];
        }
        __builtin_amdgcn_s_setprio(1);
#pragma unroll
        for (int m = 0; m < 2; ++m)
#pragma unroll
            for (int n = 0; n < 4; ++n)
                acc0[hh][m][n] = __builtin_amdgcn_mfma_f32_16x16x32_bf16(b[n], a[m], acc0[hh][m][n], 0, 0, 0);
        __builtin_amdgcn_s_setprio(0);
        __syncthreads();
    }
#pragma unroll
    for (int hh = 0; hh < 2; ++hh)
#pragma unroll
    for (int n = 0; n < 4; ++n) {
        const int ch = hh * 256 + w * 64 + n * 16 + j16 * 4;
        const float4 bv = *(const float4*)&bb0[ch];
#pragma unroll
        for (int m = 0; m < 2; ++m) {
            const int s = m * 16 + fr;
            ushort4 o;
            o.x = f2bf(fmaxf(acc0[hh][m][n][0] + bv.x, 0.f));
            o.y = f2bf(fmaxf(acc0[hh][m][n][1] + bv.y, 0.f));
            o.z = f2bf(fmaxf(acc0[hh][m][n][2] + bv.z, 0.f));
            o.w = f2bf(fmaxf(acc0[hh][m][n][3] + bv.w, 0.f));
            const int u = ch >> 3, su = u ^ (s & 7);
            *(ushort4*)&h0s[s * 512 + su * 8 + (ch & 7)] = o;
        }
    }
    __syncthreads();

    // P1: h1 = relu(h0 @ bw1^T + bb1), K=512
    f32x4 acc1[2][4] = {};
    for (int kt = 0; kt < 512; kt += 32) {
#pragma unroll
        for (int i = 0; i < 4; ++i) {
            const int idx = i * 256 + t;
            const int r = idx >> 2, u = idx & 3, us = u ^ ((r >> 1) & 3);
            stage16(bw1c + (size_t)r * 512 + kt + us * 8, &Wst[idx * 8]);
        }
        __syncthreads();
        short8v a[2], b[4];
#pragma unroll
        for (int m = 0; m < 2; ++m) {
            const int s = m * 16 + fr;
            const int u = (kt >> 3) + j16, su = u ^ (s & 7);
            a[m] = *(const short8v*)&h0s[s * 512 + su * 8];
        }
#pragma unroll
        for (int n = 0; n < 4; ++n) {
            const int lr = w * 64 + n * 16 + fr;
            b[n] = *(const short8v*)&Wst[lr * 32 + (j16 ^ ((lr >> 1) & 3)) * 8];
        }
        __builtin_amdgcn_s_setprio(1);
#pragma unroll
        for (int m = 0; m < 2; ++m)
#pragma unroll
            for (int n = 0; n < 4; ++n)
                acc1[m][n] = __builtin_amdgcn_mfma_f32_16x16x32_bf16(b[n], a[m], acc1[m][n], 0, 0, 0);
        __builtin_amdgcn_s_setprio(0);
        __syncthreads();
    }
#pragma unroll
    for (int n = 0; n < 4; ++n) {
        const int ch = w * 64 + n * 16 + j16 * 4;
        const float4 bv = *(const float4*)&bb1[ch];
#pragma unroll
        for (int m = 0; m < 2; ++m) {
            const int s = m * 16 + fr;
            ushort4 o;
            o.x = f2bf(fmaxf(acc1[m][n][0] + bv.x, 0.f));
            o.y = f2bf(fmaxf(acc1[m][n][1] + bv.y, 0.f));
            o.z = f2bf(fmaxf(acc1[m][n][2] + bv.z, 0.f));
            o.w = f2bf(fmaxf(acc1[m][n][3] + bv.w, 0.f));
            const int u = ch >> 3, su = u ^ (s & 7);
            *(ushort4*)&h1s[s * 256 + su * 8 + (ch & 7)] = o;
        }
    }
    __syncthreads();

    // P2: x_bot = relu(h1 @ bw2^T + bb2) -> Rb[B][64]
    f32x4 acc2[2] = {};
    for (int kt = 0; kt < 256; kt += 32) {
        {
            const int r = t >> 2, u = t & 3, us = u ^ ((r >> 1) & 3);
            stage16(bw2c + (size_t)r * 256 + kt + us * 8, &Wst[t * 8]);
        }
        __syncthreads();
        short8v a[2], b;
#pragma unroll
        for (int m = 0; m < 2; ++m) {
            const int s = m * 16 + fr;
            const int u = (kt >> 3) + j16, su = u ^ (s & 7);
            a[m] = *(const short8v*)&h1s[s * 256 + su * 8];
        }
        {
            const int lr = w * 16 + fr;
            b = *(const short8v*)&Wst[lr * 32 + (j16 ^ ((lr >> 1) & 3)) * 8];
        }
#pragma unroll
        for (int m = 0; m < 2; ++m)
            acc2[m] = __builtin_amdgcn_mfma_f32_16x16x32_bf16(b, a[m], acc2[m], 0, 0, 0);
        __syncthreads();
    }
    {
        const int ch = w * 16 + j16 * 4;
        const float4 bv = *(const float4*)&bb2[ch];
#pragma unroll
        for (int m = 0; m < 2; ++m) {
            const int s = m * 16 + fr;
            ushort4 o;
            o.x = f2bf(fmaxf(acc2[m][0] + bv.x, 0.f));
            o.y = f2bf(fmaxf(acc2[m][1] + bv.y, 0.f));
            o.z = f2bf(fmaxf(acc2[m][2] + bv.z, 0.f));
            o.w = f2bf(fmaxf(acc2[m][3] + bv.w, 0.f));
            *(ushort4*)&Rb[(size_t)(bBase + s) * 64 + ch] = o;
        }
    }
}

// ---------------------------------------------------------------------------
// Fused gather + interaction + top MLP. 32 samples/block, 4 waves.
// U unions Rt (32x424, live through phase A reads) and th0s (32x512, live
// from phase A epilogue) -> LDS 52.5 KB -> 3 blocks/CU.
// Z = T.T^T per sample via 32x32x16 MFMA with identical A/B operands.
// ---------------------------------------------------------------------------
__global__ __launch_bounds__(256, 3) void topint_k(
    const float* __restrict__ emb, const int* __restrict__ indices,
    const ushort* __restrict__ Rb, const ushort* __restrict__ tw0p,
    const float* __restrict__ tb0, const ushort* __restrict__ tw1c,
    const float* __restrict__ tb1, const float* __restrict__ tw2,
    const float* __restrict__ tb2, float* __restrict__ out)
{
    __shared__ __align__(16) ushort U[32 * 512];     // 32 KB: Rt (stride 424) then th0s (stride 512)
    __shared__ __align__(16) ushort Wst[256 * 32];   // 16 KB staging
    __shared__ __align__(16) int scratch[832];       // sidx[26][32]; reused as red[]
    const int t = threadIdx.x;
    const int lane = t & 63, w = t >> 6;
    const int fr = lane & 15, j16 = lane >> 4;
    const int bBase = blockIdx.x * 32;

    // P0: x_bot -> U-as-Rt[:, 0:64]; zero col 415; load indices
    {
        const int r = t >> 3, u = t & 7;
        short8v v = *(const short8v*)&Rb[(size_t)(bBase + r) * 64 + u * 8];
        *(short8v*)&U[r * 424 + u * 8] = v;
    }
    if (t < 32) U[t * 424 + 415] = 0;
    for (int e = t; e < 832; e += 256)
        scratch[e] = indices[(size_t)(e >> 5) * B_SZ + bBase + (e & 31)];
    __syncthreads();

    // P1: per wave-sample, Z = T.T^T via 4x mfma_32x32x16 (A == B == T fragments).
    // T row 0 = x_bot (bf16 from Rt); rows 1..26 = emb rows (fp32 -> bf16 in regs).
    {
        const int r32 = lane & 31, half = lane >> 5;
        for (int it = 0; it < 8; ++it) {
            const int s = it * 4 + w;
            short8v tf[4];
            if (r32 == 0) {
#pragma unroll
                for (int kq = 0; kq < 4; ++kq)
                    tf[kq] = *(const short8v*)&U[s * 424 + kq * 16 + half * 8];
            } else if (r32 <= 26) {
                const int idxv = scratch[(r32 - 1) * 32 + s];
                const float* rp = emb + ((size_t)(r32 - 1) * NROWS + (size_t)idxv) * 64 + half * 8;
#pragma unroll
                for (int kq = 0; kq < 4; ++kq) {
                    const float4 x = *(const float4*)&rp[kq * 16];
                    const float4 y = *(const float4*)&rp[kq * 16 + 4];
                    short8v v;
                    v[0] = (short)f2bf(x.x); v[1] = (short)f2bf(x.y);
                    v[2] = (short)f2bf(x.z); v[3] = (short)f2bf(x.w);
                    v[4] = (short)f2bf(y.x); v[5] = (short)f2bf(y.y);
                    v[6] = (short)f2bf(y.z); v[7] = (short)f2bf(y.w);
                    tf[kq] = v;
                }
            } else {
#pragma unroll
                for (int kq = 0; kq < 4; ++kq) tf[kq] = (short8v)0;
            }
            f32x16 c = {};
#pragma unroll
            for (int kq = 0; kq < 4; ++kq)
                c = __builtin_amdgcn_mfma_f32_32x32x16_bf16(tf[kq], tf[kq], c, 0, 0, 0);
            // extract strict lower triangle: row=(reg&3)+8*(reg>>2)+4*half, col=r32
#pragma unroll
            for (int reg = 0; reg < 16; ++reg) {
                const int r = (reg & 3) + 8 * (reg >> 2) + 4 * half;
                if (r < 27 && r32 < r)
                    U[s * 424 + 64 + (r * (r - 1)) / 2 + r32] = f2bf(c[reg]);
            }
        }
    }
    __syncthreads();

    // phase A: th0 = relu(R @ tw0^T + tb0), K=416, 2 channel halves of 256
    f32x4 accA[2][2][4] = {};
    for (int kt = 0; kt < 416; kt += 32) {
        short8v a[2];
#pragma unroll
        for (int m = 0; m < 2; ++m) {
            const int s = m * 16 + fr;
            a[m] = *(const short8v*)&U[s * 424 + ((kt >> 3) + j16) * 8];
        }
#pragma unroll
        for (int hh = 0; hh < 2; ++hh) {
#pragma unroll
            for (int i = 0; i < 4; ++i) {
                const int idx = i * 256 + t;
                const int r = idx >> 2, u = idx & 3, us = u ^ ((r >> 1) & 3);
                stage16(tw0p + (size_t)(hh * 256 + r) * 416 + kt + us * 8, &Wst[idx * 8]);
            }
            __syncthreads();
            short8v b[4];
#pragma unroll
            for (int n = 0; n < 4; ++n) {
                const int lr = w * 64 + n * 16 + fr;
                b[n] = *(const short8v*)&Wst[lr * 32 + (j16 ^ ((lr >> 1) & 3)) * 8];
            }
            __builtin_amdgcn_s_setprio(1);
#pragma unroll
            for (int m = 0; m < 2; ++m)
#pragma unroll
                for (int n = 0; n < 4; ++n)
                    accA[hh][m][n] = __builtin_amdgcn_mfma_f32_16x16x32_bf16(b[n], a[m], accA[hh][m][n], 0, 0, 0);
            __builtin_amdgcn_s_setprio(0);
            __syncthreads();
        }
    }
    // phase A epilogue: write th0s into U (Rt is dead after the final sync above)
#pragma unroll
    for (int hh = 0; hh < 2; ++hh)
#pragma unroll
    for (int n = 0; n < 4; ++n) {
        const int ch = hh * 256 + w * 64 + n * 16 + j16 * 4;
        const float4 bv = *(const float4*)&tb0[ch];
#pragma unroll
        for (int m = 0; m < 2; ++m) {
            const int s = m * 16 + fr;
            ushort4 o;
            o.x = f2bf(fmaxf(accA[hh][m][n][0] + bv.x, 0.f));
            o.y = f2bf(fmaxf(accA[hh][m][n][1] + bv.y, 0.f));
            o.z = f2bf(fmaxf(accA[hh][m][n][2] + bv.z, 0.f));
            o.w = f2bf(fmaxf(accA[hh][m][n][3] + bv.w, 0.f));
            const int u = ch >> 3, su = u ^ (s & 7);
            *(ushort4*)&U[s * 512 + su * 8 + (ch & 7)] = o;
        }
    }
    __syncthreads();

    // phase B: th1 = relu(th0 @ tw1^T + tb1), K=512
    f32x4 acc2[2][4] = {};
    for (int kt = 0; kt < 512; kt += 32) {
#pragma unroll
        for (int i = 0; i < 4; ++i) {
            const int idx = i * 256 + t;
            const int r = idx >> 2, u = idx & 3, us = u ^ ((r >> 1) & 3);
            stage16(tw1c + (size_t)r * 512 + kt + us * 8, &Wst[idx * 8]);
        }
        __syncthreads();
        short8v a[2], b[4];
#pragma unroll
        for (int m = 0; m < 2; ++m) {
            const int s = m * 16 + fr;
            const int u = (kt >> 3) + j16, su = u ^ (s & 7);
            a[m] = *(const short8v*)&U[s * 512 + su * 8];
        }
#pragma unroll
        for (int n = 0; n < 4; ++n) {
            const int lr = w * 64 + n * 16 + fr;
            b[n] = *(const short8v*)&Wst[lr * 32 + (j16 ^ ((lr >> 1) & 3)) * 8];
        }
        __builtin_amdgcn_s_setprio(1);
#pragma unroll
        for (int m = 0; m < 2; ++m)
#pragma unroll
            for (int n = 0; n < 4; ++n)
                acc2[m][n] = __builtin_amdgcn_mfma_f32_16x16x32_bf16(b[n], a[m], acc2[m][n], 0, 0, 0);
        __builtin_amdgcn_s_setprio(0);
        __syncthreads();
    }

    // phase C: out = sigmoid( relu(th1) . tw2 + tb2 )
    float* red = (float*)scratch;
    float part[2] = {0.f, 0.f};
#pragma unroll
    for (int n = 0; n < 4; ++n) {
        const int ch = w * 64 + n * 16 + j16 * 4;
        const float4 bv = *(const float4*)&tb1[ch];
        const float4 wv = *(const float4*)&tw2[ch];
#pragma unroll
        for (int m = 0; m < 2; ++m) {
            part[m] += fmaxf(acc2[m][n][0] + bv.x, 0.f) * wv.x
                     + fmaxf(acc2[m][n][1] + bv.y, 0.f) * wv.y
                     + fmaxf(acc2[m][n][2] + bv.z, 0.f) * wv.z
                     + fmaxf(acc2[m][n][3] + bv.w, 0.f) * wv.w;
        }
    }
#pragma unroll
    for (int m = 0; m < 2; ++m) {
        float v = part[m];
        v += __shfl_xor(v, 16, 64);
        v += __shfl_xor(v, 32, 64);
        if (lane < 16) red[w * 32 + m * 16 + fr] = v;
    }
    __syncthreads();
    if (t < 32) {
        const float sm = red[t] + red[32 + t] + red[64 + t] + red[96 + t];
        out[bBase + t] = 1.f / (1.f + expf(-(sm + tb2[0])));
    }
}

extern "C" void kernel_launch(void* const* d_in, const int* in_sizes, int n_in,
                              void* d_out, int out_size, void* d_ws, size_t ws_size,
                              hipStream_t stream)
{
    (void)in_sizes; (void)n_in; (void)out_size; (void)ws_size;
    const float* dense_x = (const float*)d_in[0];
    const int*   indices = (const int*)d_in[1];
    const float* emb     = (const float*)d_in[2];
    const float* bw0 = (const float*)d_in[3];
    const float* bb0 = (const float*)d_in[4];
    const float* bw1 = (const float*)d_in[5];
    const float* bb1 = (const float*)d_in[6];
    const float* bw2 = (const float*)d_in[7];
    const float* bb2 = (const float*)d_in[8];
    const float* tw0 = (const float*)d_in[9];
    const float* tb0 = (const float*)d_in[10];
    const float* tw1 = (const float*)d_in[11];
    const float* tb1 = (const float*)d_in[12];
    const float* tw2 = (const float*)d_in[13];
    const float* tb2 = (const float*)d_in[14];
    float* out = (float*)d_out;

    ushort* ws16      = (ushort*)d_ws;
    ushort* dense_pad = ws16;                              // B x 32
    ushort* Rb        = dense_pad + (size_t)B_SZ * 32;     // B x 64 (x_bot)
    ushort* bw0p      = Rb + (size_t)B_SZ * 64;            // 512 x 32
    ushort* tw0p      = bw0p + 512 * 32;                   // 512 x 416
    ushort* bw1c      = tw0p + 512 * 416;                  // 256 x 512
    ushort* bw2c      = bw1c + 256 * 512;                  // 64 x 256
    ushort* tw1c      = bw2c + 64 * 256;                   // 256 x 512

    conv_all_k<<<dim3(6080), dim3(256), 0, stream>>>(
        dense_x, bw0, tw0, bw1, bw2, tw1,
        dense_pad, bw0p, tw0p, bw1c, bw2c, tw1c);

    bot012_k<<<dim3(B_SZ / 32), dim3(256), 0, stream>>>(
        dense_pad, bw0p, bb0, bw1c, bb1, bw2c, bb2, Rb);

    topint_k<<<dim3(B_SZ / 32), dim3(256), 0, stream>>>(
        emb, indices, Rb, tw0p, tb0, tw1c, tb1, tw2, tb2, out);
}